// Round 1
// baseline (992.100 us; speedup 1.0000x reference)
//
#include <hip/hip_runtime.h>
#include <cmath>

// Problem constants (fixed by the reference setup)
#define TT 8192        // tokens
#define NE 256         // experts
#define ND 7168        // hidden dim
#define NGRP 8
#define GSIZE 32       // experts per group (NE / NGRP)
#define TOPKG 4
#define TOPK 8
#define ROUTE_SCALE 2.5f

// GEMM tiling
#define TM 128         // tokens per block
#define TN 64          // experts per block
#define BK 32          // k-chunk

// logits[t][e] = dot(x[t,:], w[e,:])  -- fp32, vector ALU (no fp32 MFMA on CDNA4)
__global__ __launch_bounds__(256) void gemm_logits_kernel(
    const float* __restrict__ x, const float* __restrict__ w,
    float* __restrict__ logits)
{
    __shared__ float Xs[BK][TM];   // k-major: Xs[k][tok]
    __shared__ float Ws[BK][TN];   // k-major: Ws[k][exp]

    const int tid = threadIdx.x;
    const int t0 = blockIdx.x * TM;
    const int e0 = blockIdx.y * TN;
    const int tx = tid & 15;   // token lane group: tokens tx*4..tx*4+3 and 64+tx*4..
    const int ty = tid >> 4;   // expert quad: experts ty*4..ty*4+3

    float acc[8][4];
    #pragma unroll
    for (int i = 0; i < 8; ++i)
        #pragma unroll
        for (int j = 0; j < 4; ++j) acc[i][j] = 0.f;

    for (int k0 = 0; k0 < ND; k0 += BK) {
        // Stage x tile: TM x BK floats = 1024 float4, 4 per thread.
        #pragma unroll
        for (int i = 0; i < 4; ++i) {
            const int idx = tid + i * 256;
            const int row = idx >> 3;      // token row (8 float4 per row)
            const int c4  = idx & 7;       // which float4 along k
            const float4 v = *reinterpret_cast<const float4*>(
                x + (size_t)(t0 + row) * ND + (k0 + c4 * 4));
            Xs[c4 * 4 + 0][row] = v.x;
            Xs[c4 * 4 + 1][row] = v.y;
            Xs[c4 * 4 + 2][row] = v.z;
            Xs[c4 * 4 + 3][row] = v.w;
        }
        // Stage w tile: TN x BK floats = 512 float4, 2 per thread.
        #pragma unroll
        for (int i = 0; i < 2; ++i) {
            const int idx = tid + i * 256;
            const int row = idx >> 3;      // expert row
            const int c4  = idx & 7;
            const float4 v = *reinterpret_cast<const float4*>(
                w + (size_t)(e0 + row) * ND + (k0 + c4 * 4));
            Ws[c4 * 4 + 0][row] = v.x;
            Ws[c4 * 4 + 1][row] = v.y;
            Ws[c4 * 4 + 2][row] = v.z;
            Ws[c4 * 4 + 3][row] = v.w;
        }
        __syncthreads();

        #pragma unroll
        for (int kk = 0; kk < BK; ++kk) {
            // x reads: 16 lanes * float4 over 64 contiguous floats -> 2-way bank alias (free)
            const float4 a0 = *reinterpret_cast<const float4*>(&Xs[kk][tx * 4]);
            const float4 a1 = *reinterpret_cast<const float4*>(&Xs[kk][64 + tx * 4]);
            const float4 b  = *reinterpret_cast<const float4*>(&Ws[kk][ty * 4]);
            const float av[8] = {a0.x, a0.y, a0.z, a0.w, a1.x, a1.y, a1.z, a1.w};
            const float bv[4] = {b.x, b.y, b.z, b.w};
            #pragma unroll
            for (int i = 0; i < 8; ++i)
                #pragma unroll
                for (int j = 0; j < 4; ++j)
                    acc[i][j] = fmaf(av[i], bv[j], acc[i][j]);
        }
        __syncthreads();
    }

    #pragma unroll
    for (int i = 0; i < 8; ++i) {
        const int m = (i < 4) ? (tx * 4 + i) : (64 + tx * 4 + (i - 4));
        const float4 o = make_float4(acc[i][0], acc[i][1], acc[i][2], acc[i][3]);
        *reinterpret_cast<float4*>(logits + (size_t)(t0 + m) * NE + (e0 + ty * 4)) = o;
    }
}

__device__ __forceinline__ float sigmoidf_acc(float v) {
    // accurate sigmoid: libm expf (~1 ulp), matches np within fp32 noise
    return 1.0f / (1.0f + expf(-v));
}

// One thread per token: group top-2 sums -> top-4 groups -> masked top-8 experts
// -> normalized gathered sigmoid weights * 2.5.
__global__ __launch_bounds__(256) void routing_kernel(
    const float* __restrict__ logits, const float* __restrict__ bias,
    float* __restrict__ out_w, float* __restrict__ out_i)
{
    const int t = blockIdx.x * blockDim.x + threadIdx.x;
    if (t >= TT) return;
    const float* lg = logits + (size_t)t * NE;

    // Pass 1: per-group top-2 sum of (sigmoid(logit) + bias)
    float gs[NGRP];
    #pragma unroll
    for (int g = 0; g < NGRP; ++g) {
        float m1 = -1e30f, m2 = -1e30f;
        #pragma unroll
        for (int j4 = 0; j4 < GSIZE / 4; ++j4) {
            const float4 v4 = *reinterpret_cast<const float4*>(lg + g * GSIZE + j4 * 4);
            const float4 b4 = *reinterpret_cast<const float4*>(bias + g * GSIZE + j4 * 4);
            const float vs[4] = {v4.x, v4.y, v4.z, v4.w};
            const float bs[4] = {b4.x, b4.y, b4.z, b4.w};
            #pragma unroll
            for (int l = 0; l < 4; ++l) {
                const float s = sigmoidf_acc(vs[l]) + bs[l];
                if (s > m1)      { m2 = m1; m1 = s; }
                else if (s > m2) { m2 = s; }
            }
        }
        gs[g] = m1 + m2;
    }

    // Top-4 groups, strict '>' => lowest group index wins ties (jax top_k semantics)
    unsigned keep = 0;
    #pragma unroll
    for (int r = 0; r < TOPKG; ++r) {
        int best = 0; float bv = -1e30f;
        #pragma unroll
        for (int g = 0; g < NGRP; ++g) {
            const bool taken = (keep >> g) & 1u;
            if (!taken && gs[g] > bv) { bv = gs[g]; best = g; }
        }
        keep |= 1u << best;
    }

    // Pass 2: top-8 over masked scores (masked groups contribute exactly 0.0f,
    // matching sg * mask in the reference). Branchless sorted insert, strict '>'
    // so equal values keep the earlier index -> jax tie-break.
    float val[TOPK]; int idx[TOPK];
    #pragma unroll
    for (int i = 0; i < TOPK; ++i) { val[i] = -1e30f; idx[i] = 0; }

    for (int e4 = 0; e4 < NE / 4; ++e4) {
        const int g = (e4 * 4) >> 5;                    // all 4 in same group (GSIZE=32)
        const bool kept = (keep >> g) & 1u;
        const float4 v4 = *reinterpret_cast<const float4*>(lg + e4 * 4);
        const float4 b4 = *reinterpret_cast<const float4*>(bias + e4 * 4);
        const float vs[4] = {v4.x, v4.y, v4.z, v4.w};
        const float bs[4] = {b4.x, b4.y, b4.z, b4.w};
        #pragma unroll
        for (int l = 0; l < 4; ++l) {
            float cv = kept ? (sigmoidf_acc(vs[l]) + bs[l]) : 0.0f;
            int   ci = e4 * 4 + l;
            #pragma unroll
            for (int p = 0; p < TOPK; ++p) {
                const bool sw = cv > val[p];
                const float tv = val[p]; const int ti = idx[p];
                val[p] = sw ? cv : tv;   idx[p] = sw ? ci : ti;
                cv     = sw ? tv : cv;   ci     = sw ? ti : ci;
            }
        }
    }

    // Weights: gather ORIGINAL sigmoid scores (no bias), normalize, scale.
    float wv[TOPK]; float wsum = 0.f;
    #pragma unroll
    for (int i = 0; i < TOPK; ++i) {
        const float sc = sigmoidf_acc(lg[idx[i]]);
        wv[i] = sc; wsum += sc;
    }
    const float scale = ROUTE_SCALE / wsum;
    #pragma unroll
    for (int i = 0; i < TOPK; ++i) {
        out_w[(size_t)t * TOPK + i] = wv[i] * scale;
        // Indices written as float values: harness reads the concatenated
        // output buffer with the first output's dtype (fp32).
        out_i[(size_t)t * TOPK + i] = (float)idx[i];
    }
}

extern "C" void kernel_launch(void* const* d_in, const int* in_sizes, int n_in,
                              void* d_out, int out_size, void* d_ws, size_t ws_size,
                              hipStream_t stream) {
    const float* x    = (const float*)d_in[0];   // [8192, 7168]
    const float* w    = (const float*)d_in[1];   // [256, 7168]
    const float* bias = (const float*)d_in[2];   // [256]

    float* out_w = (float*)d_out;                       // [8192, 8] weights
    float* out_i = (float*)d_out + (size_t)TT * TOPK;   // [8192, 8] indices (as float)
    float* logits = (float*)d_ws;                       // 8192*256*4 = 8 MB scratch

    dim3 grid_gemm(TT / TM, NE / TN);   // (64, 4) = 256 blocks
    gemm_logits_kernel<<<grid_gemm, 256, 0, stream>>>(x, w, logits);

    routing_kernel<<<TT / 256, 256, 0, stream>>>(logits, bias, out_w, out_i);
}

// Round 2
// 415.351 us; speedup vs baseline: 2.3886x; 2.3886x over previous
//
#include <hip/hip_runtime.h>
#include <cmath>

// Problem constants
#define TT 8192
#define NE 256
#define ND 7168
#define NGRP 8
#define TOPKG 4
#define TOPK 8
#define ROUTE_SCALE 2.5f

#define NKT (ND / 32)      // 224 k-tiles of 32
#define NNT (NE / 16)      // 16 n-tiles of 16

// GEMM tiling: block = 64 tokens x 256 experts, 256 threads (4 waves),
// wave = 64 tok x 64 exp = 4x4 tiles of 16x16, K split across blockIdx.y.
#define TM 64
#define XPITCH 40          // halves per LDS row (32 + 8 pad; 80 B, 16B-aligned)

typedef _Float16 half8_ __attribute__((ext_vector_type(8)));
typedef _Float16 half4_ __attribute__((ext_vector_type(4)));
typedef float float4_ __attribute__((ext_vector_type(4)));

// ---------------------------------------------------------------------------
// w (fp32 [E][D]) -> fragment-ordered fp16 hi/lo.
// B-frag for mfma_f32_16x16x32_f16: lane holds B[k=quad*8+j][n=lane&15],
// i.e. w[n][k]. Buffer index: ((nt*NKT + kt)*64 + lane)*8 + j.
__global__ __launch_bounds__(256) void conv_w_kernel(
    const float* __restrict__ w, _Float16* __restrict__ whF,
    _Float16* __restrict__ wlF)
{
    const int gid  = blockIdx.x * 256 + threadIdx.x;   // NNT*NKT*64 total
    const int lane = gid & 63;
    const int pair = gid >> 6;            // nt*NKT + kt
    const int kt   = pair % NKT;
    const int nt   = pair / NKT;
    const int n  = nt * 16 + (lane & 15);
    const int kb = kt * 32 + (lane >> 4) * 8;
    const float* src = w + (size_t)n * ND + kb;
    const float4 v0 = *reinterpret_cast<const float4*>(src);
    const float4 v1 = *reinterpret_cast<const float4*>(src + 4);
    const float vs[8] = {v0.x, v0.y, v0.z, v0.w, v1.x, v1.y, v1.z, v1.w};
    half8_ h, l;
    #pragma unroll
    for (int j = 0; j < 8; ++j) {
        const _Float16 hi = (_Float16)vs[j];
        h[j] = hi;
        l[j] = (_Float16)(vs[j] - (float)hi);
    }
    const size_t off = ((size_t)pair * 64 + lane) * 8;
    *reinterpret_cast<half8_*>(whF + off) = h;
    *reinterpret_cast<half8_*>(wlF + off) = l;
}

// ---------------------------------------------------------------------------
// Split-fp16 MFMA GEMM: partial[ks][t][e] = sum_{k in slice} x[t][k] w[e][k]
__global__ __launch_bounds__(256, 2) void gemm_kernel(
    const float* __restrict__ x, const _Float16* __restrict__ whF,
    const _Float16* __restrict__ wlF, float* __restrict__ partial,
    int K_slice)
{
    __shared__ _Float16 Xh[TM][XPITCH];
    __shared__ _Float16 Xl[TM][XPITCH];

    const int tid  = threadIdx.x;
    const int lane = tid & 63;
    const int nq   = tid >> 6;            // wave id -> expert quarter (64 wide)
    const int t0   = blockIdx.x * TM;
    const int ks   = blockIdx.y;
    const int kbeg = ks * K_slice;
    const int kt0  = kbeg >> 5;
    const int nchunks = K_slice >> 5;

    const int q  = lane >> 4;             // quad
    const int cn = lane & 15;

    float4_ acc[4][4];
    #pragma unroll
    for (int i = 0; i < 4; ++i)
        #pragma unroll
        for (int j = 0; j < 4; ++j) acc[i][j] = (float4_)0.0f;

    // staging map: float4 id f = tid + i*256 (i=0,1); row = f>>3, c4 = f&7
    const int srow0 = tid >> 3;
    const int sc4   = tid & 7;

    for (int c = 0; c < nchunks; ++c) {
        const int k0 = kbeg + c * 32;
        // Stage + convert x chunk: 64 x 32 fp32 -> hi/lo fp16 LDS tiles
        #pragma unroll
        for (int i = 0; i < 2; ++i) {
            const int row = srow0 + i * 32;
            const float4 v = *reinterpret_cast<const float4*>(
                x + (size_t)(t0 + row) * ND + k0 + sc4 * 4);
            const float vs[4] = {v.x, v.y, v.z, v.w};
            half4_ h, l;
            #pragma unroll
            for (int j = 0; j < 4; ++j) {
                const _Float16 hi = (_Float16)vs[j];
                h[j] = hi;
                l[j] = (_Float16)(vs[j] - (float)hi);
            }
            *reinterpret_cast<half4_*>(&Xh[row][sc4 * 4]) = h;
            *reinterpret_cast<half4_*>(&Xl[row][sc4 * 4]) = l;
        }
        __syncthreads();

        // A-frags: lane holds A[m=lane&15][k=quad*8+j]
        half8_ ah[4], al[4];
        #pragma unroll
        for (int mt = 0; mt < 4; ++mt) {
            ah[mt] = *reinterpret_cast<const half8_*>(&Xh[mt * 16 + cn][q * 8]);
            al[mt] = *reinterpret_cast<const half8_*>(&Xl[mt * 16 + cn][q * 8]);
        }
        // B-frags straight from global (L2-resident, fragment-ordered)
        const int kt = kt0 + c;
        half8_ bh[4], bl[4];
        #pragma unroll
        for (int ntl = 0; ntl < 4; ++ntl) {
            const size_t off =
                ((size_t)((nq * 4 + ntl) * NKT + kt) * 64 + lane) * 8;
            bh[ntl] = *reinterpret_cast<const half8_*>(whF + off);
            bl[ntl] = *reinterpret_cast<const half8_*>(wlF + off);
        }
        #pragma unroll
        for (int mt = 0; mt < 4; ++mt)
            #pragma unroll
            for (int ntl = 0; ntl < 4; ++ntl) {
                acc[mt][ntl] = __builtin_amdgcn_mfma_f32_16x16x32_f16(
                    ah[mt], bh[ntl], acc[mt][ntl], 0, 0, 0);
                acc[mt][ntl] = __builtin_amdgcn_mfma_f32_16x16x32_f16(
                    al[mt], bh[ntl], acc[mt][ntl], 0, 0, 0);
                acc[mt][ntl] = __builtin_amdgcn_mfma_f32_16x16x32_f16(
                    ah[mt], bl[ntl], acc[mt][ntl], 0, 0, 0);
            }
        __syncthreads();
    }

    // Epilogue: C/D layout col=lane&15, row=quad*4+reg
    #pragma unroll
    for (int mt = 0; mt < 4; ++mt)
        #pragma unroll
        for (int r = 0; r < 4; ++r) {
            const int t = t0 + mt * 16 + q * 4 + r;
            float* rowp = partial + ((size_t)ks * TT + t) * NE;
            #pragma unroll
            for (int ntl = 0; ntl < 4; ++ntl)
                rowp[nq * 64 + ntl * 16 + cn] = acc[mt][ntl][r];
        }
}

// ---------------------------------------------------------------------------
// Routing: one 64-lane wave per token; lane handles 4 experts.
__global__ __launch_bounds__(256) void routing_kernel(
    const float* __restrict__ partial, const float* __restrict__ bias,
    float* __restrict__ out_w, float* __restrict__ out_i, int kslices)
{
    const int lane = threadIdx.x & 63;
    const int t = blockIdx.x * 4 + (threadIdx.x >> 6);

    // Sum K-slice partials (deterministic order)
    float4 a = make_float4(0.f, 0.f, 0.f, 0.f);
    for (int s = 0; s < kslices; ++s) {
        const float4 p = *reinterpret_cast<const float4*>(
            partial + ((size_t)s * TT + t) * NE + lane * 4);
        a.x += p.x; a.y += p.y; a.z += p.z; a.w += p.w;
    }
    const float4 b4 = *reinterpret_cast<const float4*>(bias + lane * 4);
    const float lg[4] = {a.x, a.y, a.z, a.w};
    const float bs[4] = {b4.x, b4.y, b4.z, b4.w};
    float sg[4], sv[4];
    #pragma unroll
    for (int j = 0; j < 4; ++j) {
        sg[j] = 1.0f / (1.0f + expf(-lg[j]));   // original sigmoid score
        sv[j] = sg[j] + bs[j];                  // biased score
    }

    // Per-group (8 lanes = 32 experts) top-2 sum
    float m1 = -1e30f, m2 = -1e30f;
    #pragma unroll
    for (int j = 0; j < 4; ++j) {
        if (sv[j] > m1)      { m2 = m1; m1 = sv[j]; }
        else if (sv[j] > m2) { m2 = sv[j]; }
    }
    #pragma unroll
    for (int off = 1; off <= 4; off <<= 1) {
        const float o1 = __shfl_xor(m1, off, 64);
        const float o2 = __shfl_xor(m2, off, 64);
        if (o1 > m1) { m2 = fmaxf(m1, o2); m1 = o1; }
        else         { m2 = fmaxf(m2, o1); }
    }
    const float gs = m1 + m2;

    // All 8 group scores on every lane; serial top-4 (lowest index on ties)
    float gv[NGRP];
    #pragma unroll
    for (int g = 0; g < NGRP; ++g) gv[g] = __shfl(gs, g * 8, 64);
    unsigned keep = 0;
    #pragma unroll
    for (int r = 0; r < TOPKG; ++r) {
        int best = 0; float bvv = -1e30f;
        #pragma unroll
        for (int g = 0; g < NGRP; ++g) {
            const bool taken = (keep >> g) & 1u;
            if (!taken && gv[g] > bvv) { bvv = gv[g]; best = g; }
        }
        keep |= 1u << best;
    }

    // Masked scores (exact 0.0f for dropped groups, matching sg*mask)
    const bool kept = (keep >> (lane >> 3)) & 1u;
    float rv[4];
    #pragma unroll
    for (int j = 0; j < 4; ++j) rv[j] = kept ? sv[j] : 0.0f;

    // 8x wave argmax extraction carrying (biased val, idx, orig sigmoid)
    float wsum = 0.f, myw = 0.f;
    int myi = 0;
    #pragma unroll
    for (int r = 0; r < TOPK; ++r) {
        float bv = -1e30f, bo = 0.f; int bi = 0x7fffffff;
        #pragma unroll
        for (int j = 0; j < 4; ++j)
            if (rv[j] > bv) { bv = rv[j]; bi = lane * 4 + j; bo = sg[j]; }
        #pragma unroll
        for (int off = 1; off < 64; off <<= 1) {
            const float ov = __shfl_xor(bv, off, 64);
            const int   oi = __shfl_xor(bi, off, 64);
            const float oo = __shfl_xor(bo, off, 64);
            if (ov > bv || (ov == bv && oi < bi)) { bv = ov; bi = oi; bo = oo; }
        }
        if ((bi >> 2) == lane) rv[bi & 3] = -1e30f;   // remove winner
        wsum += bo;
        if (lane == r) { myw = bo; myi = bi; }
    }
    const float scale = ROUTE_SCALE / wsum;
    if (lane < TOPK) {
        out_w[(size_t)t * TOPK + lane] = myw * scale;
        out_i[(size_t)t * TOPK + lane] = (float)myi;  // fp32-encoded indices
    }
}

// ---------------------------------------------------------------------------
extern "C" void kernel_launch(void* const* d_in, const int* in_sizes, int n_in,
                              void* d_out, int out_size, void* d_ws, size_t ws_size,
                              hipStream_t stream) {
    const float* x    = (const float*)d_in[0];
    const float* w    = (const float*)d_in[1];
    const float* bias = (const float*)d_in[2];

    float* out_w = (float*)d_out;
    float* out_i = (float*)d_out + (size_t)TT * TOPK;

    // ws layout: whF | wlF | partial[kslices][TT][NE]
    const size_t wfrag_bytes = (size_t)NE * ND * sizeof(_Float16);  // 3.67 MB
    _Float16* whF = (_Float16*)d_ws;
    _Float16* wlF = (_Float16*)((char*)d_ws + wfrag_bytes);
    float* partial = (float*)((char*)d_ws + 2 * wfrag_bytes);

    const size_t part1 = (size_t)TT * NE * sizeof(float);           // 8 MB
    int kslices = 1;
    if (ws_size >= 2 * wfrag_bytes + 4 * part1) kslices = 4;
    else if (ws_size >= 2 * wfrag_bytes + 2 * part1) kslices = 2;
    const int K_slice = ND / kslices;

    conv_w_kernel<<<(NNT * NKT * 64) / 256, 256, 0, stream>>>(w, whF, wlF);

    dim3 ggrid(TT / TM, kslices);   // (128, 4) = 512 blocks
    gemm_kernel<<<ggrid, 256, 0, stream>>>(x, whF, wlF, partial, K_slice);

    routing_kernel<<<TT / 4, 256, 0, stream>>>(partial, bias, out_w, out_i, kslices);
}

// Round 3
// 390.866 us; speedup vs baseline: 2.5382x; 1.0626x over previous
//
#include <hip/hip_runtime.h>
#include <cmath>

// Problem constants
#define TT 8192
#define NE 256
#define ND 7168
#define NGRP 8
#define TOPKG 4
#define TOPK 8
#define ROUTE_SCALE 2.5f

#define NKT (ND / 32)      // 224 k-tiles of 32
#define NNT (NE / 16)      // 16 n-tiles of 16

// GEMM tiling: block = 64 tokens x 256 experts, 256 threads (4 waves),
// wave = 64 tok x 64 exp = 4x4 tiles of 16x16, K split across blockIdx.y.
#define TM 64
#define XPITCH 40          // halves per LDS row (32 + 8 pad): b128 reads 2-way alias = free
#define BSTRN ((size_t)NKT * 512)   // halves between 16-expert n-tiles in frag buffer

typedef _Float16 half8_ __attribute__((ext_vector_type(8)));
typedef _Float16 half4_ __attribute__((ext_vector_type(4)));
typedef float float4_ __attribute__((ext_vector_type(4)));

// ---------------------------------------------------------------------------
// w (fp32 [E][D]) -> fragment-ordered fp16 hi/lo.
// B-frag for mfma_f32_16x16x32_f16: lane holds B[k=quad*8+j][n=lane&15].
__global__ __launch_bounds__(256) void conv_w_kernel(
    const float* __restrict__ w, _Float16* __restrict__ whF,
    _Float16* __restrict__ wlF)
{
    const int gid  = blockIdx.x * 256 + threadIdx.x;   // NNT*NKT*64 total
    const int lane = gid & 63;
    const int pair = gid >> 6;            // nt*NKT + kt
    const int kt   = pair % NKT;
    const int nt   = pair / NKT;
    const int n  = nt * 16 + (lane & 15);
    const int kb = kt * 32 + (lane >> 4) * 8;
    const float* src = w + (size_t)n * ND + kb;
    const float4 v0 = *reinterpret_cast<const float4*>(src);
    const float4 v1 = *reinterpret_cast<const float4*>(src + 4);
    const float vs[8] = {v0.x, v0.y, v0.z, v0.w, v1.x, v1.y, v1.z, v1.w};
    half8_ h, l;
    #pragma unroll
    for (int j = 0; j < 8; ++j) {
        const _Float16 hi = (_Float16)vs[j];
        h[j] = hi;
        l[j] = (_Float16)(vs[j] - (float)hi);
    }
    const size_t off = ((size_t)pair * 64 + lane) * 8;
    *reinterpret_cast<half8_*>(whF + off) = h;
    *reinterpret_cast<half8_*>(wlF + off) = l;
}

// ---------------------------------------------------------------------------
// Split-fp16 MFMA GEMM, software-pipelined:
//   - LDS double buffer for x (hi/lo fp16), ONE barrier per 32-k chunk
//   - B frags prefetched 1 chunk ahead (registers, L2-resident source)
//   - x prefetched 2 chunks ahead (registers, HBM source)
// Slot convention: register slot s holds data for chunk with (chunk & 1) == s.
__global__ __launch_bounds__(256, 2) void gemm_kernel(
    const float* __restrict__ x, const _Float16* __restrict__ whF,
    const _Float16* __restrict__ wlF, float* __restrict__ partial,
    int K_slice)
{
    __shared__ _Float16 XhL[2][TM * XPITCH];
    __shared__ _Float16 XlL[2][TM * XPITCH];

    const int tid  = threadIdx.x;
    const int lane = tid & 63;
    const int nq   = tid >> 6;            // wave id -> 64-expert quarter
    const int t0   = blockIdx.x * TM;
    const int ks   = blockIdx.y;
    const int kbeg = ks * K_slice;
    const int kt0  = kbeg >> 5;
    const int nchunks = K_slice >> 5;     // always even (28/56/112/224)

    const int q  = lane >> 4;             // quad
    const int cn = lane & 15;
    const int srow0 = tid >> 3;           // staging row (0..31)
    const int sc4   = tid & 7;            // staging float4 col

    float4_ acc[4][4];
    #pragma unroll
    for (int i = 0; i < 4; ++i)
        #pragma unroll
        for (int j = 0; j < 4; ++j) acc[i][j] = (float4_)0.0f;

    const float* xp0 = x + (size_t)(t0 + srow0) * ND + kbeg + sc4 * 4;
    const float* xp1 = xp0 + (size_t)32 * ND;
    const _Float16* bh0 = whF + (size_t)(nq * 4) * BSTRN + (size_t)kt0 * 512 + lane * 8;
    const _Float16* bl0 = wlF + (size_t)(nq * 4) * BSTRN + (size_t)kt0 * 512 + lane * 8;

    float4 xv[2][2];       // x stage regs: [slot][row-half]
    half8_ Bf[2][8];       // B frags: [slot][ntl*2 + (0=hi,1=lo)]

    // Prologue: x(0)->slot0, x(1)->slot1, B(0)->slot0; stage x(0) into LDS buf0.
    xv[0][0] = *reinterpret_cast<const float4*>(xp0);
    xv[0][1] = *reinterpret_cast<const float4*>(xp1);
    xv[1][0] = *reinterpret_cast<const float4*>(xp0 + 32);
    xv[1][1] = *reinterpret_cast<const float4*>(xp1 + 32);
    #pragma unroll
    for (int ntl = 0; ntl < 4; ++ntl) {
        Bf[0][ntl * 2 + 0] = *reinterpret_cast<const half8_*>(bh0 + (size_t)ntl * BSTRN);
        Bf[0][ntl * 2 + 1] = *reinterpret_cast<const half8_*>(bl0 + (size_t)ntl * BSTRN);
    }
    #pragma unroll
    for (int i = 0; i < 2; ++i) {
        const float4 v = xv[0][i];
        const float vs[4] = {v.x, v.y, v.z, v.w};
        half4_ h, l;
        #pragma unroll
        for (int j = 0; j < 4; ++j) {
            const _Float16 hi = (_Float16)vs[j];
            h[j] = hi; l[j] = (_Float16)(vs[j] - (float)hi);
        }
        const int soff = (srow0 + i * 32) * XPITCH + sc4 * 4;
        *reinterpret_cast<half4_*>(&XhL[0][soff]) = h;
        *reinterpret_cast<half4_*>(&XlL[0][soff]) = l;
    }
    __syncthreads();

#define STEP(P, C)                                                           \
    {                                                                        \
        if ((C) + 2 < nchunks) { /* x(C+2) -> slot P (freed: x(C) staged) */ \
            xv[P][0] = *reinterpret_cast<const float4*>(xp0 + ((C) + 2) * 32); \
            xv[P][1] = *reinterpret_cast<const float4*>(xp1 + ((C) + 2) * 32); \
        }                                                                    \
        if ((C) + 1 < nchunks) { /* B(C+1) -> slot P^1 */                    \
            _Pragma("unroll")                                                \
            for (int ntl = 0; ntl < 4; ++ntl) {                              \
                Bf[(P) ^ 1][ntl * 2 + 0] = *reinterpret_cast<const half8_*>( \
                    bh0 + (size_t)ntl * BSTRN + ((C) + 1) * 512);            \
                Bf[(P) ^ 1][ntl * 2 + 1] = *reinterpret_cast<const half8_*>( \
                    bl0 + (size_t)ntl * BSTRN + ((C) + 1) * 512);            \
            }                                                                \
        }                                                                    \
        half8_ ah[4], al[4];                                                 \
        _Pragma("unroll")                                                    \
        for (int mt = 0; mt < 4; ++mt) {                                     \
            ah[mt] = *reinterpret_cast<const half8_*>(                       \
                &XhL[P][(mt * 16 + cn) * XPITCH + q * 8]);                   \
            al[mt] = *reinterpret_cast<const half8_*>(                       \
                &XlL[P][(mt * 16 + cn) * XPITCH + q * 8]);                   \
        }                                                                    \
        _Pragma("unroll")                                                    \
        for (int mt = 0; mt < 4; ++mt)                                       \
            _Pragma("unroll")                                                \
            for (int ntl = 0; ntl < 4; ++ntl) {                              \
                acc[mt][ntl] = __builtin_amdgcn_mfma_f32_16x16x32_f16(       \
                    ah[mt], Bf[P][ntl * 2 + 0], acc[mt][ntl], 0, 0, 0);      \
                acc[mt][ntl] = __builtin_amdgcn_mfma_f32_16x16x32_f16(       \
                    al[mt], Bf[P][ntl * 2 + 0], acc[mt][ntl], 0, 0, 0);      \
                acc[mt][ntl] = __builtin_amdgcn_mfma_f32_16x16x32_f16(       \
                    ah[mt], Bf[P][ntl * 2 + 1], acc[mt][ntl], 0, 0, 0);      \
            }                                                                \
        if ((C) + 1 < nchunks) { /* stage x(C+1) from slot P^1 -> buf P^1 */ \
            _Pragma("unroll")                                                \
            for (int i = 0; i < 2; ++i) {                                    \
                const float4 v = xv[(P) ^ 1][i];                             \
                const float vs[4] = {v.x, v.y, v.z, v.w};                    \
                half4_ h, l;                                                 \
                _Pragma("unroll")                                            \
                for (int j = 0; j < 4; ++j) {                                \
                    const _Float16 hi = (_Float16)vs[j];                     \
                    h[j] = hi; l[j] = (_Float16)(vs[j] - (float)hi);         \
                }                                                            \
                const int soff = (srow0 + i * 32) * XPITCH + sc4 * 4;        \
                *reinterpret_cast<half4_*>(&XhL[(P) ^ 1][soff]) = h;         \
                *reinterpret_cast<half4_*>(&XlL[(P) ^ 1][soff]) = l;         \
            }                                                                \
        }                                                                    \
        __syncthreads();                                                     \
    }

    for (int c = 0; c < nchunks; c += 2) {
        STEP(0, c)
        STEP(1, c + 1)
    }
#undef STEP

    // Epilogue: C/D layout col=lane&15, row=quad*4+reg
    #pragma unroll
    for (int mt = 0; mt < 4; ++mt)
        #pragma unroll
        for (int r = 0; r < 4; ++r) {
            const int t = t0 + mt * 16 + q * 4 + r;
            float* rowp = partial + ((size_t)ks * TT + t) * NE;
            #pragma unroll
            for (int ntl = 0; ntl < 4; ++ntl)
                rowp[nq * 64 + ntl * 16 + cn] = acc[mt][ntl][r];
        }
}

// ---------------------------------------------------------------------------
// Routing: one 64-lane wave per token; lane handles 4 experts.
__global__ __launch_bounds__(256) void routing_kernel(
    const float* __restrict__ partial, const float* __restrict__ bias,
    float* __restrict__ out_w, float* __restrict__ out_i, int kslices)
{
    const int lane = threadIdx.x & 63;
    const int t = blockIdx.x * 4 + (threadIdx.x >> 6);

    float4 a = make_float4(0.f, 0.f, 0.f, 0.f);
    for (int s = 0; s < kslices; ++s) {
        const float4 p = *reinterpret_cast<const float4*>(
            partial + ((size_t)s * TT + t) * NE + lane * 4);
        a.x += p.x; a.y += p.y; a.z += p.z; a.w += p.w;
    }
    const float4 b4 = *reinterpret_cast<const float4*>(bias + lane * 4);
    const float lg[4] = {a.x, a.y, a.z, a.w};
    const float bs[4] = {b4.x, b4.y, b4.z, b4.w};
    float sg[4], sv[4];
    #pragma unroll
    for (int j = 0; j < 4; ++j) {
        sg[j] = 1.0f / (1.0f + expf(-lg[j]));   // original sigmoid score
        sv[j] = sg[j] + bs[j];                  // biased score
    }

    // Per-group (8 lanes = 32 experts) top-2 sum
    float m1 = -1e30f, m2 = -1e30f;
    #pragma unroll
    for (int j = 0; j < 4; ++j) {
        if (sv[j] > m1)      { m2 = m1; m1 = sv[j]; }
        else if (sv[j] > m2) { m2 = sv[j]; }
    }
    #pragma unroll
    for (int off = 1; off <= 4; off <<= 1) {
        const float o1 = __shfl_xor(m1, off, 64);
        const float o2 = __shfl_xor(m2, off, 64);
        if (o1 > m1) { m2 = fmaxf(m1, o2); m1 = o1; }
        else         { m2 = fmaxf(m2, o1); }
    }
    const float gs = m1 + m2;

    // All 8 group scores on every lane; serial top-4 (lowest index on ties)
    float gv[NGRP];
    #pragma unroll
    for (int g = 0; g < NGRP; ++g) gv[g] = __shfl(gs, g * 8, 64);
    unsigned keep = 0;
    #pragma unroll
    for (int r = 0; r < TOPKG; ++r) {
        int best = 0; float bvv = -1e30f;
        #pragma unroll
        for (int g = 0; g < NGRP; ++g) {
            const bool taken = (keep >> g) & 1u;
            if (!taken && gv[g] > bvv) { bvv = gv[g]; best = g; }
        }
        keep |= 1u << best;
    }

    // Masked scores (exact 0.0f for dropped groups, matching sg*mask)
    const bool kept = (keep >> (lane >> 3)) & 1u;
    float rv[4];
    #pragma unroll
    for (int j = 0; j < 4; ++j) rv[j] = kept ? sv[j] : 0.0f;

    // 8x wave argmax extraction carrying (biased val, idx, orig sigmoid)
    float wsum = 0.f, myw = 0.f;
    int myi = 0;
    #pragma unroll
    for (int r = 0; r < TOPK; ++r) {
        float bv = -1e30f, bo = 0.f; int bi = 0x7fffffff;
        #pragma unroll
        for (int j = 0; j < 4; ++j)
            if (rv[j] > bv) { bv = rv[j]; bi = lane * 4 + j; bo = sg[j]; }
        #pragma unroll
        for (int off = 1; off < 64; off <<= 1) {
            const float ov = __shfl_xor(bv, off, 64);
            const int   oi = __shfl_xor(bi, off, 64);
            const float oo = __shfl_xor(bo, off, 64);
            if (ov > bv || (ov == bv && oi < bi)) { bv = ov; bi = oi; bo = oo; }
        }
        if ((bi >> 2) == lane) rv[bi & 3] = -1e30f;   // remove winner
        wsum += bo;
        if (lane == r) { myw = bo; myi = bi; }
    }
    const float scale = ROUTE_SCALE / wsum;
    if (lane < TOPK) {
        out_w[(size_t)t * TOPK + lane] = myw * scale;
        out_i[(size_t)t * TOPK + lane] = (float)myi;  // fp32-encoded indices
    }
}

// ---------------------------------------------------------------------------
extern "C" void kernel_launch(void* const* d_in, const int* in_sizes, int n_in,
                              void* d_out, int out_size, void* d_ws, size_t ws_size,
                              hipStream_t stream) {
    const float* x    = (const float*)d_in[0];
    const float* w    = (const float*)d_in[1];
    const float* bias = (const float*)d_in[2];

    float* out_w = (float*)d_out;
    float* out_i = (float*)d_out + (size_t)TT * TOPK;

    // ws layout: whF | wlF | partial[kslices][TT][NE]
    const size_t wfrag_bytes = (size_t)NE * ND * sizeof(_Float16);  // 3.67 MB
    _Float16* whF = (_Float16*)d_ws;
    _Float16* wlF = (_Float16*)((char*)d_ws + wfrag_bytes);
    float* partial = (float*)((char*)d_ws + 2 * wfrag_bytes);

    const size_t part1 = (size_t)TT * NE * sizeof(float);           // 8 MB
    int kslices = 1;
    if      (ws_size >= 2 * wfrag_bytes + 8 * part1) kslices = 8;
    else if (ws_size >= 2 * wfrag_bytes + 4 * part1) kslices = 4;
    else if (ws_size >= 2 * wfrag_bytes + 2 * part1) kslices = 2;
    const int K_slice = ND / kslices;

    conv_w_kernel<<<(NNT * NKT * 64) / 256, 256, 0, stream>>>(w, whF, wlF);

    dim3 ggrid(TT / TM, kslices);
    gemm_kernel<<<ggrid, 256, 0, stream>>>(x, whF, wlF, partial, K_slice);

    routing_kernel<<<TT / 4, 256, 0, stream>>>(partial, bias, out_w, out_i, kslices);
}